// Round 8
// baseline (16195.052 us; speedup 1.0000x reference)
//
#include <hip/hip_runtime.h>
#include <math.h>

#define NSTEP 4095   // T-1 sequence steps
#define EDIM  512
#define HDIM  1024
#define GDIM  4096   // 4*H
#define KDIM  1024   // 2E == H == 1024 for both GEMMs
#define CDIM  1221
#define SNWG  64     // scan workgroups
#define UNITS 16     // hidden units per scan WG

__device__ __forceinline__ float sigmoidf_(float v) {
    return 1.0f / (1.0f + __expf(-v));
}
__device__ __forceinline__ float tanhf_(float v) {
    v = fminf(fmaxf(v, -15.0f), 15.0f);      // avoid inf/inf NaN
    const float e2 = __expf(2.0f * v);
    return (e2 - 1.0f) / (e2 + 1.0f);
}

// ---------------------------------------------------------------------------
// GEMM1: xg[m][n] = sum_k A[m][k]*W_ih[n][k] + b_ih[n] + b_hh[n]
//   A[m][k] = emb[x[m]][k] (k<512) ; emb[x[4095]][k-512] (k>=512)
// ---------------------------------------------------------------------------
__global__ __launch_bounds__(256) void gemm_emb_kernel(
    const int* __restrict__ x, const float* __restrict__ emb,
    const float* __restrict__ W, const float* __restrict__ b_ih,
    const float* __restrict__ b_hh, float* __restrict__ xg)
{
    __shared__ float As[8][128];
    __shared__ float Bs[8][128];
    const int tid = threadIdx.x;
    const int bm = blockIdx.y * 128, bn = blockIdx.x * 128;
    const int tx = tid & 15, ty = tid >> 4;
    const int lrow = tid >> 1;
    const int lk4  = (tid & 1) * 4;
    const int lastTok = x[NSTEP];
    const int am = bm + lrow;
    const int tokRow = (am < NSTEP) ? x[am] : 0;
    const int bnrow = bn + lrow;

    float acc[8][8];
#pragma unroll
    for (int i = 0; i < 8; ++i)
#pragma unroll
        for (int j = 0; j < 8; ++j) acc[i][j] = 0.0f;

    for (int k0 = 0; k0 < KDIM; k0 += 8) {
        const int k = k0 + lk4;
        float4 av = make_float4(0.f, 0.f, 0.f, 0.f);
        if (am < NSTEP) {
            const int tok = (k < EDIM) ? tokRow : lastTok;
            const int kk  = (k < EDIM) ? k : (k - EDIM);
            av = *(const float4*)(emb + (size_t)tok * EDIM + kk);
        }
        const float4 bv = *(const float4*)(W + (size_t)bnrow * KDIM + k);
        __syncthreads();
        As[lk4 + 0][lrow] = av.x; As[lk4 + 1][lrow] = av.y;
        As[lk4 + 2][lrow] = av.z; As[lk4 + 3][lrow] = av.w;
        Bs[lk4 + 0][lrow] = bv.x; Bs[lk4 + 1][lrow] = bv.y;
        Bs[lk4 + 2][lrow] = bv.z; Bs[lk4 + 3][lrow] = bv.w;
        __syncthreads();
#pragma unroll
        for (int kk = 0; kk < 8; ++kk) {
            const float4 a0 = *(const float4*)&As[kk][ty * 4];
            const float4 a1 = *(const float4*)&As[kk][ty * 4 + 64];
            const float4 b0 = *(const float4*)&Bs[kk][tx * 4];
            const float4 b1 = *(const float4*)&Bs[kk][tx * 4 + 64];
            const float a[8] = {a0.x, a0.y, a0.z, a0.w, a1.x, a1.y, a1.z, a1.w};
            const float b[8] = {b0.x, b0.y, b0.z, b0.w, b1.x, b1.y, b1.z, b1.w};
#pragma unroll
            for (int i = 0; i < 8; ++i)
#pragma unroll
                for (int j = 0; j < 8; ++j) acc[i][j] += a[i] * b[j];
        }
    }
#pragma unroll
    for (int i = 0; i < 8; ++i) {
        const int m = bm + ((i < 4) ? (ty * 4 + i) : (64 + ty * 4 + i - 4));
        if (m >= NSTEP) continue;
#pragma unroll
        for (int j = 0; j < 8; ++j) {
            const int n = bn + ((j < 4) ? (tx * 4 + j) : (64 + tx * 4 + j - 4));
            xg[(size_t)m * GDIM + n] = acc[i][j] + b_ih[n] + b_hh[n];
        }
    }
}

// ---------------------------------------------------------------------------
// GEMM2: out[m][n] = sum_k hs[m][k]*W_out[n][k] + b_out[n]   (N=1221)
// ---------------------------------------------------------------------------
__global__ __launch_bounds__(256) void gemm_out_kernel(
    const float* __restrict__ A, const float* __restrict__ W,
    const float* __restrict__ bias, float* __restrict__ C)
{
    __shared__ float As[8][128];
    __shared__ float Bs[8][128];
    const int tid = threadIdx.x;
    const int bm = blockIdx.y * 128, bn = blockIdx.x * 128;
    const int tx = tid & 15, ty = tid >> 4;
    const int lrow = tid >> 1;
    const int lk4  = (tid & 1) * 4;
    const int am = bm + lrow;
    const int bnrow = bn + lrow;

    float acc[8][8];
#pragma unroll
    for (int i = 0; i < 8; ++i)
#pragma unroll
        for (int j = 0; j < 8; ++j) acc[i][j] = 0.0f;

    for (int k0 = 0; k0 < KDIM; k0 += 8) {
        const int k = k0 + lk4;
        float4 av = make_float4(0.f, 0.f, 0.f, 0.f);
        if (am < NSTEP) av = *(const float4*)(A + (size_t)am * KDIM + k);
        float4 bv = make_float4(0.f, 0.f, 0.f, 0.f);
        if (bnrow < CDIM) bv = *(const float4*)(W + (size_t)bnrow * KDIM + k);
        __syncthreads();
        As[lk4 + 0][lrow] = av.x; As[lk4 + 1][lrow] = av.y;
        As[lk4 + 2][lrow] = av.z; As[lk4 + 3][lrow] = av.w;
        Bs[lk4 + 0][lrow] = bv.x; Bs[lk4 + 1][lrow] = bv.y;
        Bs[lk4 + 2][lrow] = bv.z; Bs[lk4 + 3][lrow] = bv.w;
        __syncthreads();
#pragma unroll
        for (int kk = 0; kk < 8; ++kk) {
            const float4 a0 = *(const float4*)&As[kk][ty * 4];
            const float4 a1 = *(const float4*)&As[kk][ty * 4 + 64];
            const float4 b0 = *(const float4*)&Bs[kk][tx * 4];
            const float4 b1 = *(const float4*)&Bs[kk][tx * 4 + 64];
            const float a[8] = {a0.x, a0.y, a0.z, a0.w, a1.x, a1.y, a1.z, a1.w};
            const float b[8] = {b0.x, b0.y, b0.z, b0.w, b1.x, b1.y, b1.z, b1.w};
#pragma unroll
            for (int i = 0; i < 8; ++i)
#pragma unroll
                for (int j = 0; j < 8; ++j) acc[i][j] += a[i] * b[j];
        }
    }
#pragma unroll
    for (int i = 0; i < 8; ++i) {
        const int m = bm + ((i < 4) ? (ty * 4 + i) : (64 + ty * 4 + i - 4));
        if (m >= NSTEP) continue;
#pragma unroll
        for (int j = 0; j < 8; ++j) {
            const int n = bn + ((j < 4) ? (tx * 4 + j) : (64 + tx * 4 + j - 4));
            if (n < CDIM) C[(size_t)m * CDIM + n] = acc[i][j] + bias[n];
        }
    }
}

// ---------------------------------------------------------------------------
// Persistent LSTM scan, v9 = v3 with ONE change: gate rows remapped so wave
// w owns all 4 gate rows of unit g*16+w (lane = q*16+seg, row q*HDIM+unit).
// Everything else is v3 byte-for-byte: 64 WGs x 1024 threads, same per-thread
// weight shape (16 float4, cols i*64+seg*4), same h_s read pattern, same
// tid-linear poll of all 1024 tagged hb words, same publish scheme.
// What the remap buys (v3's measured intra-step serial tail): after the
// 4-stage seg-butterfly the 4 gate sums sit in lanes 0/16/32/48 of the SAME
// wave -> 4 in-wave broadcasts replace the gate_s LDS round-trip, barrier C,
// and the 16-thread (1008 idle lanes) nonlinearity block. c lives in a
// register (redundant per-lane). One barrier per step.
// Dropping barrier C is WAR-safe because h_s is parity double-buffered:
// our thread's t+2 write to h_s[par] <= it saw tag t+1 on its unit <= that
// unit's owner passed its spin at t+1 (saw ALL units @t) <= OUR waves
// published t <= our step-t reads of h_s[par] were complete. hb's own
// 2-step slack proof is unchanged from v3.
// ---------------------------------------------------------------------------
__global__ __launch_bounds__(1024, 4) void scan_kernel(
    const float* __restrict__ xg, const float* __restrict__ Whh,
    float* __restrict__ hs, unsigned long long* hb)
{
    __shared__ float h_s[2][HDIM];               // parity double-buffer (8KB)
    const int g = blockIdx.x, tid = threadIdx.x;
    const int w = tid >> 6, lane = tid & 63;     // wave w owns unit g*16+w
    const int q = lane >> 4, seg = lane & 15;    // gate q, 16 segs x 64 cols
    const int unit = g * UNITS + w;
    const int grow = q * HDIM + unit;            // gate row in W_hh

    // weights: thread covers cols i*64 + seg*4 .. +3, i = 0..15 (v3 shape)
    float4 w4[16];
#pragma unroll
    for (int i = 0; i < 16; ++i)
        w4[i] = *(const float4*)(Whh + (size_t)grow * KDIM + i * 64 + seg * 4);

    for (int i = tid; i < 2 * HDIM; i += 1024) ((float*)h_s)[i] = 0.0f;
    __syncthreads();

    float c = 0.0f;                              // redundant per-lane cell

    for (int t = 1; t <= NSTEP; ++t) {
        const int par = (t - 1) & 1;

        // xg load overlaps the spin below (lanes 0/16/32/48 fetch gate q)
        float xgv = 0.0f;
        if (seg == 0) xgv = xg[(size_t)(t - 1) * GDIM + grow];

        if (t > 1) {
            const int want = t - 1;
            unsigned long long v;
            for (;;) {
                v = __hip_atomic_load(&hb[par * HDIM + tid], __ATOMIC_RELAXED,
                                      __HIP_MEMORY_SCOPE_AGENT);
                if ((int)(v >> 32) == want) break;   // per-lane spin
            }
            h_s[par][tid] = __uint_as_float((unsigned)v);
        }
        __syncthreads();   // (B) h_s[par] ready -- the only barrier per step

        // GEMV: this thread's 64 columns of its gate row (xg folded pre-reduce)
        float acc = (seg == 0) ? xgv : 0.0f;
#pragma unroll
        for (int i = 0; i < 16; ++i) {
            const float4 h4 = *(const float4*)&h_s[par][i * 64 + seg * 4];
            acc += w4[i].x * h4.x + w4[i].y * h4.y +
                   w4[i].z * h4.z + w4[i].w * h4.w;
        }
        // 4-stage butterfly over the 16 segs of each gate-row group
        acc += __shfl_xor(acc, 1, 64);
        acc += __shfl_xor(acc, 2, 64);
        acc += __shfl_xor(acc, 4, 64);
        acc += __shfl_xor(acc, 8, 64);
        // gather the 4 gate sums in-wave (constant lanes -> broadcasts)
        const float g0 = __shfl(acc,  0, 64);    // i
        const float g1 = __shfl(acc, 16, 64);    // f
        const float g2 = __shfl(acc, 32, 64);    // g
        const float g3 = __shfl(acc, 48, 64);    // o

        const float ig = sigmoidf_(g0);
        const float fg = sigmoidf_(g1);
        const float gg = tanhf_(g2);
        const float og = sigmoidf_(g3);
        c = fg * c + ig * gg;
        const float h = og * tanhf_(c);

        if (lane == 0) {
            hs[(size_t)(t - 1) * HDIM + unit] = h;
            const unsigned long long pv =
                ((unsigned long long)(unsigned)t << 32) | __float_as_uint(h);
            __hip_atomic_store(&hb[(t & 1) * HDIM + unit], pv,
                               __ATOMIC_RELAXED, __HIP_MEMORY_SCOPE_AGENT);
        }
        // no trailing barrier: h_s parity + the handoff ordering proof above
        // make next-iteration h_s writes WAR-safe; hb overwrite at t+2 is
        // gated by the 2-step production slack (v3 proof unchanged).
    }
}

extern "C" void kernel_launch(void* const* d_in, const int* in_sizes, int n_in,
                              void* d_out, int out_size, void* d_ws, size_t ws_size,
                              hipStream_t stream)
{
    const int*   x     = (const int*)d_in[0];
    const float* emb   = (const float*)d_in[1];
    const float* W_ih  = (const float*)d_in[2];
    const float* W_hh  = (const float*)d_in[3];
    const float* b_ih  = (const float*)d_in[4];
    const float* b_hh  = (const float*)d_in[5];
    const float* W_out = (const float*)d_in[6];
    const float* b_out = (const float*)d_in[7];
    float* out = (float*)d_out;

    float* xg = (float*)d_ws;                          // 4095*4096 f32
    float* hs = xg + (size_t)NSTEP * GDIM;             // 4095*1024 f32
    unsigned long long* hb =
        (unsigned long long*)(hs + (size_t)NSTEP * HDIM);  // 2*1024 u64 (8B aligned)

    dim3 blk(256);
    dim3 g1(GDIM / 128, 32);                           // 32 x 32
    gemm_emb_kernel<<<g1, blk, 0, stream>>>(x, emb, W_ih, b_ih, b_hh, xg);

    scan_kernel<<<dim3(SNWG), dim3(1024), 0, stream>>>(xg, W_hh, hs, hb);

    dim3 g2((CDIM + 127) / 128, 32);                   // 10 x 32
    gemm_out_kernel<<<g2, blk, 0, stream>>>(hs, W_out, b_out, out);
}